// Round 1
// baseline (4836.759 us; speedup 1.0000x reference)
//
#include <hip/hip_runtime.h>
#include <math.h>

#define FIN 512
#define AD 64
#define FO 256
#define FO4 (FO / 4)
#define MAXIT 200

// scalar slots (double)
#define S_GAM0 0   // gamma parity slot 0
#define S_GAM1 1   // gamma parity slot 1
#define S_PAP  2
#define S_BS   3
#define S_ATOL2 4

__device__ __forceinline__ double block_reduce256(double v) {
    __shared__ double sh[4];
    int lane = threadIdx.x & 63;
    int w = threadIdx.x >> 6;
#pragma unroll
    for (int s = 32; s; s >>= 1) v += __shfl_down(v, s, 64);
    if (lane == 0) sh[w] = v;
    __syncthreads();
    double r = 0.0;
    if (threadIdx.x == 0) r = sh[0] + sh[1] + sh[2] + sh[3];
    return r;
}

// C[M,Nc] = A[M,K] @ W[K,Nc] + bias ; 64x64 tile, 256 threads, 4x4 microtile
__global__ __launch_bounds__(256) void gemm_bias(
    const float* __restrict__ A, const float* __restrict__ W,
    const float* __restrict__ bias, float* __restrict__ C,
    int M, int K, int Nc) {
    __shared__ float As[16][65];
    __shared__ float Ws[16][64];
    const int bm = blockIdx.x * 64;
    const int bn = blockIdx.y * 64;
    const int tid = threadIdx.x;
    const int tm = (tid >> 4) << 2;
    const int tn = (tid & 15) << 2;
    const int lr = tid >> 2;
    const int lk = (tid & 3) << 2;
    const int kr = tid >> 4;
    const int kc = (tid & 15) << 2;
    float acc[4][4] = {};
    for (int k0 = 0; k0 < K; k0 += 16) {
        float4 av = make_float4(0.f, 0.f, 0.f, 0.f);
        int arow = bm + lr;
        if (arow < M) av = *(const float4*)&A[(long)arow * K + k0 + lk];
        As[lk + 0][lr] = av.x; As[lk + 1][lr] = av.y;
        As[lk + 2][lr] = av.z; As[lk + 3][lr] = av.w;
        *(float4*)&Ws[kr][kc] = *(const float4*)&W[(long)(k0 + kr) * Nc + bn + kc];
        __syncthreads();
#pragma unroll
        for (int kk = 0; kk < 16; ++kk) {
            float a0 = As[kk][tm + 0], a1 = As[kk][tm + 1],
                  a2 = As[kk][tm + 2], a3 = As[kk][tm + 3];
            float b0 = Ws[kk][tn + 0], b1 = Ws[kk][tn + 1],
                  b2 = Ws[kk][tn + 2], b3 = Ws[kk][tn + 3];
            acc[0][0] += a0 * b0; acc[0][1] += a0 * b1; acc[0][2] += a0 * b2; acc[0][3] += a0 * b3;
            acc[1][0] += a1 * b0; acc[1][1] += a1 * b1; acc[1][2] += a1 * b2; acc[1][3] += a1 * b3;
            acc[2][0] += a2 * b0; acc[2][1] += a2 * b1; acc[2][2] += a2 * b2; acc[2][3] += a2 * b3;
            acc[3][0] += a3 * b0; acc[3][1] += a3 * b1; acc[3][2] += a3 * b2; acc[3][3] += a3 * b3;
        }
        __syncthreads();
    }
#pragma unroll
    for (int i = 0; i < 4; ++i) {
        int rowi = bm + tm + i;
        if (rowi < M) {
#pragma unroll
            for (int j = 0; j < 4; ++j)
                C[(long)rowi * Nc + bn + tn + j] = acc[i][j] + bias[bn + tn + j];
        }
    }
}

// one wave per edge: vals[e] = sigmoid(<attn[row], attn[col]>); deg += ; cnt += 1
__global__ __launch_bounds__(256) void edge_vals_k(
    const int* __restrict__ row, const int* __restrict__ col,
    const float* __restrict__ attn, float* __restrict__ vals,
    float* __restrict__ deg, int* __restrict__ cnt, int E) {
    int wid = (blockIdx.x * blockDim.x + threadIdx.x) >> 6;
    int lane = threadIdx.x & 63;
    if (wid >= E) return;
    int r = row[wid], c = col[wid];
    float a = attn[r * AD + lane] * attn[c * AD + lane];
#pragma unroll
    for (int s = 32; s; s >>= 1) a += __shfl_down(a, s, 64);
    if (lane == 0) {
        float v = 1.0f / (1.0f + __expf(-a));
        vals[wid] = v;
        unsafeAtomicAdd(&deg[r], v);
        atomicAdd(&cnt[r], 1);
    }
}

__global__ void dinv_k(float* deg, int n) {
    int i = blockIdx.x * blockDim.x + threadIdx.x;
    if (i < n) {
        float d = deg[i];
        deg[i] = d > 0.0f ? rsqrtf(d) : 0.0f;
    }
}

// single-block exclusive scan cnt -> rowptr, rowptr[n] = total
__global__ __launch_bounds__(1024) void scan_k(
    const int* __restrict__ cnt, int* __restrict__ rowptr, int n) {
    __shared__ int sh[1024];
    __shared__ int carry;
    int tid = threadIdx.x;
    if (tid == 0) carry = 0;
    __syncthreads();
    for (int base = 0; base < n; base += 1024) {
        int i = base + tid;
        int v = (i < n) ? cnt[i] : 0;
        sh[tid] = v;
        __syncthreads();
        for (int ofs = 1; ofs < 1024; ofs <<= 1) {
            int t = (tid >= ofs) ? sh[tid - ofs] : 0;
            __syncthreads();
            sh[tid] += t;
            __syncthreads();
        }
        int incl = sh[tid];
        int cbase = carry;
        __syncthreads();
        if (i < n) rowptr[i] = cbase + incl - v;
        if (tid == 1023) carry = cbase + incl;
        __syncthreads();
    }
    if (tid == 0) rowptr[n] = carry;
}

__global__ void scatter_k(
    const int* __restrict__ row, const int* __restrict__ col,
    const float* __restrict__ vals, const float* __restrict__ dinv,
    const int* __restrict__ rowptr, int* __restrict__ cursor,
    int* __restrict__ csr_c, float* __restrict__ csr_w, int E) {
    int e = blockIdx.x * blockDim.x + threadIdx.x;
    if (e >= E) return;
    int r = row[e], c = col[e];
    int pos = rowptr[r] + atomicAdd(&cursor[r], 1);
    csr_c[pos] = c;
    csr_w[pos] = vals[e] * dinv[r] * dinv[c];
}

// p = r (=b) ; bs = <b,b>
__global__ __launch_bounds__(256) void cg_init(
    const float4* __restrict__ b4, float4* __restrict__ p4,
    double* __restrict__ scal, int total4) {
    double loc = 0.0;
    int stride = gridDim.x * blockDim.x;
    for (int i = blockIdx.x * blockDim.x + threadIdx.x; i < total4; i += stride) {
        float4 v = b4[i];
        p4[i] = v;
        loc += (double)(v.x * v.x + v.y * v.y + v.z * v.z + v.w * v.w);
    }
    double tot = block_reduce256(loc);
    if (threadIdx.x == 0) unsafeAtomicAdd(&scal[S_BS], tot);
}

__global__ void cg_init2(double* scal) {
    if (threadIdx.x == 0 && blockIdx.x == 0) {
        double bs = scal[S_BS];
        scal[S_GAM0] = bs;
        scal[S_ATOL2] = 1e-10 * bs;  // (tol=1e-5)^2 * <b,b>
    }
}

// Ap = p - coef * Anorm p (CSR pull, 4 rows/wave) ; pAp partial
__global__ __launch_bounds__(256) void cg_spmm(
    const int* __restrict__ rowptr, const int* __restrict__ csr_c,
    const float* __restrict__ csr_w, const float4* __restrict__ p4,
    float4* __restrict__ ap4, double* __restrict__ scal,
    const int* __restrict__ flag, const float* __restrict__ eps_inv,
    int n, int it) {
    if (*flag) return;
    if (blockIdx.x == 0 && threadIdx.x == 0) scal[(it + 1) & 1] = 0.0;  // zero gamma_new
    const float coef = 1.0f / (1.0f + __expf(eps_inv[0]));  // 1 - sigmoid(z)
    const int lane = threadIdx.x & 63;
    const int wid = (blockIdx.x << 2) + (threadIdx.x >> 6);
    const int r0 = wid << 2;
    double dacc = 0.0;
    for (int rr = 0; rr < 4; ++rr) {
        int rowi = r0 + rr;
        if (rowi < n) {
            int js = rowptr[rowi], je = rowptr[rowi + 1];
            float4 acc = make_float4(0.f, 0.f, 0.f, 0.f);
            for (int j0 = js; j0 < je; j0 += 64) {
                int rem = je - j0;
                int cj = 0;
                float wj = 0.0f;
                if (lane < rem) { cj = csr_c[j0 + lane]; wj = csr_w[j0 + lane]; }
                int cntc = rem < 64 ? rem : 64;
                for (int t = 0; t < cntc; ++t) {
                    int c = __shfl(cj, t, 64);
                    float ww = __shfl(wj, t, 64);
                    float4 v = p4[c * FO4 + lane];
                    acc.x += ww * v.x; acc.y += ww * v.y;
                    acc.z += ww * v.z; acc.w += ww * v.w;
                }
            }
            float4 pv = p4[rowi * FO4 + lane];
            float4 ap;
            ap.x = pv.x - coef * acc.x;
            ap.y = pv.y - coef * acc.y;
            ap.z = pv.z - coef * acc.z;
            ap.w = pv.w - coef * acc.w;
            ap4[rowi * FO4 + lane] = ap;
            dacc += (double)(pv.x * ap.x + pv.y * ap.y + pv.z * ap.z + pv.w * ap.w);
        }
    }
    double tot = block_reduce256(dacc);
    if (threadIdx.x == 0) unsafeAtomicAdd(&scal[S_PAP], tot);
}

// alpha = gamma/pAp ; x += alpha p ; r -= alpha Ap ; gamma_new = <r,r> partial
__global__ __launch_bounds__(256) void cg_axpy(
    float4* __restrict__ x4, float4* __restrict__ r4,
    const float4* __restrict__ p4, const float4* __restrict__ ap4,
    double* __restrict__ scal, const int* __restrict__ flag,
    int total4, int it) {
    if (*flag) return;
    const float alpha = (float)(scal[it & 1] / scal[S_PAP]);
    double loc = 0.0;
    int stride = gridDim.x * blockDim.x;
    for (int i = blockIdx.x * blockDim.x + threadIdx.x; i < total4; i += stride) {
        float4 pv = p4[i], av = ap4[i], xv = x4[i], rv = r4[i];
        xv.x += alpha * pv.x; xv.y += alpha * pv.y;
        xv.z += alpha * pv.z; xv.w += alpha * pv.w;
        rv.x -= alpha * av.x; rv.y -= alpha * av.y;
        rv.z -= alpha * av.z; rv.w -= alpha * av.w;
        x4[i] = xv; r4[i] = rv;
        loc += (double)(rv.x * rv.x + rv.y * rv.y + rv.z * rv.z + rv.w * rv.w);
    }
    double tot = block_reduce256(loc);
    if (threadIdx.x == 0) unsafeAtomicAdd(&scal[(it + 1) & 1], tot);
}

// beta = gamma_new/gamma ; p = r + beta p ; converge check ; pAp reset
__global__ __launch_bounds__(256) void cg_pupd(
    float4* __restrict__ p4, const float4* __restrict__ r4,
    double* __restrict__ scal, int* __restrict__ flag,
    int total4, int it) {
    if (*flag) return;
    const double gnew = scal[(it + 1) & 1];
    const float beta = (float)(gnew / scal[it & 1]);
    int stride = gridDim.x * blockDim.x;
    for (int i = blockIdx.x * blockDim.x + threadIdx.x; i < total4; i += stride) {
        float4 pv = p4[i], rv = r4[i];
        pv.x = rv.x + beta * pv.x; pv.y = rv.y + beta * pv.y;
        pv.z = rv.z + beta * pv.z; pv.w = rv.w + beta * pv.w;
        p4[i] = pv;
    }
    if (blockIdx.x == 0 && threadIdx.x == 0) {
        scal[S_PAP] = 0.0;
        if (gnew <= scal[S_ATOL2]) *flag = 1;  // matches jax cond: rs > atol2
    }
}

extern "C" void kernel_launch(void* const* d_in, const int* in_sizes, int n_in,
                              void* d_out, int out_size, void* d_ws, size_t ws_size,
                              hipStream_t stream) {
    const int* row = (const int*)d_in[0];
    const int* col = (const int*)d_in[1];
    const float* feat = (const float*)d_in[2];
    const float* Wa = (const float*)d_in[3];
    const float* ba = (const float*)d_in[4];
    const float* Wo = (const float*)d_in[5];
    const float* bo = (const float*)d_in[6];
    const float* eps_inv = (const float*)d_in[7];
    const int E = in_sizes[0];
    const int n = in_sizes[2] / FIN;
    const int total4 = n * FO4;

    char* w = (char*)d_ws;
    size_t off = 0;
    auto alloc = [&](size_t bytes) -> void* {
        void* p = w + off;
        off += (bytes + 255) & ~(size_t)255;
        return p;
    };
    float* r_vec = (float*)alloc((size_t)n * FO * 4);
    float* p_vec = (float*)alloc((size_t)n * FO * 4);
    float* ap_vec = (float*)alloc((size_t)n * FO * 4);
    float* attn = (float*)alloc((size_t)n * AD * 4);
    float* vals = (float*)alloc((size_t)E * 4);
    float* csr_w_arr = (float*)alloc((size_t)E * 4);
    int* csr_c = (int*)alloc((size_t)E * 4);
    int* rowptr = (int*)alloc((size_t)(n + 1) * 4);
    // contiguous zero-block: deg(n f32) | cnt(n i32) | cursor(n i32) | scal(8 dbl) | flag
    size_t zb_bytes = (size_t)n * 12 + 64 + 16;
    char* zb = (char*)alloc(zb_bytes);
    float* deg = (float*)zb;
    int* cnt = (int*)(zb + (size_t)n * 4);
    int* cursor = (int*)(zb + (size_t)n * 8);
    double* scal = (double*)(zb + (size_t)n * 12);
    int* flag = (int*)(zb + (size_t)n * 12 + 64);

    hipMemsetAsync(d_out, 0, (size_t)out_size * 4, stream);
    hipMemsetAsync(zb, 0, zb_bytes, stream);

    dim3 blk(256);
    dim3 g1((n + 63) / 64, AD / 64);
    gemm_bias<<<g1, blk, 0, stream>>>(feat, Wa, ba, attn, n, FIN, AD);
    dim3 g2((n + 63) / 64, FO / 64);
    gemm_bias<<<g2, blk, 0, stream>>>(feat, Wo, bo, r_vec, n, FIN, FO);

    edge_vals_k<<<(E + 3) / 4, 256, 0, stream>>>(row, col, attn, vals, deg, cnt, E);
    dinv_k<<<(n + 255) / 256, 256, 0, stream>>>(deg, n);
    scan_k<<<1, 1024, 0, stream>>>(cnt, rowptr, n);
    scatter_k<<<(E + 255) / 256, 256, 0, stream>>>(row, col, vals, deg, rowptr, cursor,
                                                   csr_c, csr_w_arr, E);

    cg_init<<<2048, 256, 0, stream>>>((const float4*)r_vec, (float4*)p_vec, scal, total4);
    cg_init2<<<1, 64, 0, stream>>>(scal);

    float4* x4 = (float4*)d_out;
    int spmm_blocks = (n + 15) / 16;
    for (int it = 0; it < MAXIT; ++it) {
        cg_spmm<<<spmm_blocks, 256, 0, stream>>>(rowptr, csr_c, csr_w_arr,
                                                 (const float4*)p_vec, (float4*)ap_vec,
                                                 scal, flag, eps_inv, n, it);
        cg_axpy<<<2048, 256, 0, stream>>>(x4, (float4*)r_vec, (const float4*)p_vec,
                                          (const float4*)ap_vec, scal, flag, total4, it);
        cg_pupd<<<2048, 256, 0, stream>>>((float4*)p_vec, (const float4*)r_vec, scal, flag,
                                          total4, it);
    }
}